// Round 6
// baseline (452.086 us; speedup 1.0000x reference)
//
#include <hip/hip_runtime.h>
#include <hip/hip_bf16.h>
#include <math.h>

typedef __bf16 bf16_t;
typedef bf16_t bf16x8 __attribute__((ext_vector_type(8)));
typedef bf16_t bf16x4 __attribute__((ext_vector_type(4)));
typedef float f32x4 __attribute__((ext_vector_type(4)));
typedef int i32x4 __attribute__((ext_vector_type(4)));
typedef unsigned int u32;

#define B_SZ 4096
#define P_HID 1024
#define H_HID 512
#define MAX_P 128
#define MAX_HE 42
#define HE_PAD 128          // W2h BT padded to 128 rows so G2h shares G2p's shape
#define E_MAX 8128
#define E_MAX4 2032

// ---------------------------------------------------------------------------
__device__ __forceinline__ void async_cp16(const bf16_t* g, bf16_t* l) {
    __builtin_amdgcn_global_load_lds(
        (const __attribute__((address_space(1))) u32*)g,
        (__attribute__((address_space(3))) u32*)l, 16, 0, 0);
}

__device__ __forceinline__ float gelu_exact(float v) {
    return 0.5f * v * (1.f + erff(v * 0.70710678118654752f));
}

// ---------------------------------------------------------------------------
// gemm_pack: R4-proven structure (do not touch — A/B anchor at 274.4 us).
// Packed split-bf16 3-MFMA GEMM, 2-phase pipelined, BM=64 uniform,
// 4 waves 2x2, 48KB LDS -> 3 blocks/CU (the R5 BM=128 variant dropped to
// 2 blocks/CU and regressed +16us: occupancy beats per-wave MFMA ratio here).
// ---------------------------------------------------------------------------
struct GemmP {
    const bf16_t *Ahi, *Alo, *BThi, *BTlo;
    const float* bias;
    bf16_t *Chi, *Clo;            // MODE 0
    const float* g;               // MODE 1
    float *out_mask, *out_n;      // MODE 1
    int *ws_n;                    // MODE 1 (optional)
    int N, K, NV, nx;             // nx = blocks along N
};

template<int MODE, int BM>
__global__ __launch_bounds__(256, 3) void gemm_pack(GemmP P, GemmP H, int pBlocks)
{
    constexpr int BN = 128;
    constexpr int MT = BM / 32;            // 2 (MODE0)
    constexpr int NT = 4;                  // wave covers 64 cols
    constexpr int OPS_A = BM / 16;         // staging ops per A plane
    constexpr int OPS_B = BN / 16;         // 8 per B plane
    constexpr int NOPS = 2 * OPS_A + 2 * OPS_B;
    constexpr int TILE = NOPS * 16 * 32;   // elems per k-tile buffer

    __shared__ __align__(16) bf16_t smem[2 * TILE];
    __shared__ float cnt[BM][2];

    const bool isP = (int)blockIdx.x < pBlocks;
    const GemmP& a = isP ? P : H;
    const int bid  = isP ? blockIdx.x : blockIdx.x - pBlocks;
    const int bn   = (bid % a.nx) * BN;
    const int bm   = (bid / a.nx) * BM;
    const int K    = a.K;

    const int tid  = threadIdx.x;
    const int lane = tid & 63;
    const int wid  = tid >> 6;
    const int wm   = wid & 1;              // row half
    const int wn   = wid >> 1;             // col half

    const int srow = lane >> 2;            // staging row within a 16-row op
    const int scol = (lane & 3) * 8;       // staging k-offset (bf16 elems)
    const int fr   = lane & 15;
    const int fq   = lane >> 4;

    f32x4 acc[MT][NT];
#pragma unroll
    for (int i = 0; i < MT; ++i)
#pragma unroll
        for (int j = 0; j < NT; ++j)
            acc[i][j] = (f32x4){0.f, 0.f, 0.f, 0.f};

    const bf16_t* const gA0 = a.Ahi  + (size_t)bm * K;
    const bf16_t* const gA1 = a.Alo  + (size_t)bm * K;
    const bf16_t* const gB0 = a.BThi + (size_t)bn * K;
    const bf16_t* const gB1 = a.BTlo + (size_t)bn * K;

    auto stage = [&](int buf, int kt) {
#pragma unroll
        for (int o = 0; o < NOPS; ++o) {
            if ((o & 3) != wid) continue;
            const bf16_t* gsrc;
            int q, sec;
            if (o < OPS_A)                  { q = o;                     gsrc = gA0; sec = 0; }
            else if (o < 2 * OPS_A)         { q = o - OPS_A;             gsrc = gA1; sec = BM * 32; }
            else if (o < 2 * OPS_A + OPS_B) { q = o - 2 * OPS_A;         gsrc = gB0; sec = 2 * BM * 32; }
            else                            { q = o - 2 * OPS_A - OPS_B; gsrc = gB1; sec = 2 * BM * 32 + BN * 32; }
            async_cp16(gsrc + (size_t)(q * 16 + srow) * K + kt + scol,
                       smem + buf * TILE + sec + q * 16 * 32);
        }
    };

    // ---- 2-phase pipelined K loop ----
    stage(0, 0);
    __syncthreads();
    int cur = 0;
    for (int kt = 0; kt < K; kt += 32) {
        if (kt + 32 < K) stage(cur ^ 1, kt + 32);   // issue next tile EARLY

        const bf16_t* const Tb = smem + cur * TILE;
        bf16x8 ah[MT], al[MT];
#pragma unroll
        for (int i = 0; i < MT; ++i) {
            const int row = wm * (BM / 2) + i * 16 + fr;
            ah[i] = *(const bf16x8*)(Tb + row * 32 + fq * 8);
            al[i] = *(const bf16x8*)(Tb + BM * 32 + row * 32 + fq * 8);
        }
#pragma unroll
        for (int j = 0; j < NT; ++j) {
            const int row = wn * 64 + j * 16 + fr;
            const bf16x8 bh = *(const bf16x8*)(Tb + 2 * BM * 32 + row * 32 + fq * 8);
            const bf16x8 bl = *(const bf16x8*)(Tb + 2 * BM * 32 + BN * 32 + row * 32 + fq * 8);
#pragma unroll
            for (int i = 0; i < MT; ++i) {
                acc[i][j] = __builtin_amdgcn_mfma_f32_16x16x32_bf16(ah[i], bh, acc[i][j], 0, 0, 0);
                acc[i][j] = __builtin_amdgcn_mfma_f32_16x16x32_bf16(ah[i], bl, acc[i][j], 0, 0, 0);
                acc[i][j] = __builtin_amdgcn_mfma_f32_16x16x32_bf16(al[i], bh, acc[i][j], 0, 0, 0);
            }
        }
        __syncthreads();
        cur ^= 1;
    }

    // ---- epilogue ----  C/D layout: col = lane&15, row = (lane>>4)*4 + reg
    if (MODE == 0) {
#pragma unroll
        for (int i = 0; i < MT; ++i)
#pragma unroll
            for (int j = 0; j < NT; ++j) {
                const int col  = bn + wn * 64 + j * 16 + fr;
                const int row0 = bm + wm * (BM / 2) + i * 16 + fq * 4;
                const float bj = a.bias[col];
#pragma unroll
                for (int r = 0; r < 4; ++r) {
                    float v = gelu_exact(acc[i][j][r] + bj);
                    bf16_t h = (bf16_t)v;
                    bf16_t l = (bf16_t)(v - (float)h);
                    const size_t off = (size_t)(row0 + r) * a.N + col;
                    a.Chi[off] = h;
                    a.Clo[off] = l;
                }
            }
    } else {
        const int NV = a.NV;
#pragma unroll
        for (int i = 0; i < MT; ++i) {
#pragma unroll
            for (int r = 0; r < 4; ++r) {
                const int row_l = wm * (BM / 2) + i * 16 + fq * 4 + r;
                const int grow  = bm + row_l;
                float s = 0.f;
#pragma unroll
                for (int j = 0; j < NT; ++j) {
                    const int col = wn * 64 + j * 16 + fr;
                    if (col < NV) {
                        const float v = acc[i][j][r] + a.bias[col];
                        const size_t idx = (size_t)grow * NV + col;
                        const float g0 = a.g[2 * idx + 0];
                        const float g1 = a.g[2 * idx + 1];
                        const float m = ((v + g0) > (g1 - v)) ? 1.f : 0.f;
                        a.out_mask[idx] = m;
                        s += m;
                    }
                }
                s += __shfl_xor(s, 1, 64);
                s += __shfl_xor(s, 2, 64);
                s += __shfl_xor(s, 4, 64);
                s += __shfl_xor(s, 8, 64);
                if (fr == 0) cnt[row_l][wn] = s;
            }
        }
        __syncthreads();
        if (tid < BM) {
            const float c = cnt[tid][0] + cnt[tid][1];
            a.out_n[bm + tid] = c;
            if (a.ws_n) a.ws_n[bm + tid] = (int)c;
        }
    }
}

// ---------------------------------------------------------------------------
// gemm_logit_sk: split-K x4 logit GEMM + gumbel epilogue (last-arrival).
// Old gemm<1> ran 256 blocks = 1 block/CU = 1 wave/SIMD: nothing hides the
// per-step stage latency. Split-K x4 -> 1024 blocks, 40KB LDS -> 4 blocks/CU.
// Each split writes a deterministic f32 partial tile; the last-arriving split
// (device-scope counter) sums the 4 partials in FIXED order and runs the
// gumbel mask/count epilogue (deterministic, no FP atomics).
// ---------------------------------------------------------------------------
struct GemmSK {
    const bf16_t *Ahi, *Alo, *BThi, *BTlo;
    const float* bias;
    const float* g;
    float *out_mask, *out_n;
    int *ws_n;                 // optional
    float* part;               // [tiles][SPLITS][32][128] f32 partials
    int* cnt;                  // [tiles] arrival counters (pre-zeroed by prep)
    int K, NV;
};

__global__ __launch_bounds__(256, 4) void gemm_logit_sk(GemmSK P, GemmSK H, int pBlocks)
{
    constexpr int SPLITS = 4;
    constexpr int BM = 32, BN = 128, NT = 4;
    constexpr int OPS_A = BM / 16;                 // 2 per plane
    constexpr int OPS_B = BN / 16;                 // 8 per plane
    constexpr int NOPS  = 2 * OPS_A + 2 * OPS_B;   // 20
    constexpr int TILE  = NOPS * 16 * 32;          // 10240 elems = 20 KB

    __shared__ __align__(16) bf16_t smem[2 * TILE];   // 40 KB, no extras

    const bool isP = (int)blockIdx.x < pBlocks;
    const GemmSK& a = isP ? P : H;
    const int bid   = isP ? blockIdx.x : blockIdx.x - pBlocks;
    const int tile  = bid >> 2;
    const int split = bid & (SPLITS - 1);
    const int bm    = tile * BM;
    const int K     = a.K;
    const int Ksub  = K / SPLITS;
    const int k0    = split * Ksub;

    const int tid  = threadIdx.x;
    const int lane = tid & 63;
    const int wid  = tid >> 6;
    const int wm   = wid & 1;              // 16-row half
    const int wn   = wid >> 1;             // 64-col half

    const int srow = lane >> 2;
    const int scol = (lane & 3) * 8;
    const int fr   = lane & 15;
    const int fq   = lane >> 4;

    f32x4 acc[NT];
#pragma unroll
    for (int j = 0; j < NT; ++j) acc[j] = (f32x4){0.f, 0.f, 0.f, 0.f};

    const bf16_t* const gA0 = a.Ahi  + (size_t)bm * K + k0;
    const bf16_t* const gA1 = a.Alo  + (size_t)bm * K + k0;
    const bf16_t* const gB0 = a.BThi + k0;             // bn == 0
    const bf16_t* const gB1 = a.BTlo + k0;

    auto stage = [&](int buf, int kt) {
#pragma unroll
        for (int o = 0; o < NOPS; ++o) {
            if ((o & 3) != wid) continue;
            const bf16_t* gsrc;
            int q, sec;
            if (o < OPS_A)                  { q = o;                     gsrc = gA0; sec = 0; }
            else if (o < 2 * OPS_A)         { q = o - OPS_A;             gsrc = gA1; sec = BM * 32; }
            else if (o < 2 * OPS_A + OPS_B) { q = o - 2 * OPS_A;         gsrc = gB0; sec = 2 * BM * 32; }
            else                            { q = o - 2 * OPS_A - OPS_B; gsrc = gB1; sec = 2 * BM * 32 + BN * 32; }
            async_cp16(gsrc + (size_t)(q * 16 + srow) * K + kt + scol,
                       smem + buf * TILE + sec + q * 16 * 32);
        }
    };

    stage(0, 0);
    __syncthreads();
    int cur = 0;
    for (int kt = 0; kt < Ksub; kt += 32) {
        if (kt + 32 < Ksub) stage(cur ^ 1, kt + 32);

        const bf16_t* const Tb = smem + cur * TILE;
        const int arow = wm * 16 + fr;
        const bf16x8 ah = *(const bf16x8*)(Tb + arow * 32 + fq * 8);
        const bf16x8 al = *(const bf16x8*)(Tb + BM * 32 + arow * 32 + fq * 8);
#pragma unroll
        for (int j = 0; j < NT; ++j) {
            const int brow = wn * 64 + j * 16 + fr;
            const bf16x8 bh = *(const bf16x8*)(Tb + 2 * BM * 32 + brow * 32 + fq * 8);
            const bf16x8 bl = *(const bf16x8*)(Tb + 2 * BM * 32 + BN * 32 + brow * 32 + fq * 8);
            acc[j] = __builtin_amdgcn_mfma_f32_16x16x32_bf16(ah, bh, acc[j], 0, 0, 0);
            acc[j] = __builtin_amdgcn_mfma_f32_16x16x32_bf16(ah, bl, acc[j], 0, 0, 0);
            acc[j] = __builtin_amdgcn_mfma_f32_16x16x32_bf16(al, bh, acc[j], 0, 0, 0);
        }
        __syncthreads();
        cur ^= 1;
    }

    // ---- write this split's partial tile (plain row-major f32) ----
    float* const pt = a.part + ((size_t)tile * SPLITS + split) * (BM * BN);
#pragma unroll
    for (int j = 0; j < NT; ++j)
#pragma unroll
        for (int r = 0; r < 4; ++r) {
            const int row_l = wm * 16 + fq * 4 + r;
            const int col   = wn * 64 + j * 16 + fr;
            pt[row_l * BN + col] = acc[j][r];
        }
    __threadfence();
    __syncthreads();

    int* const sflag = (int*)smem;          // LDS dead now — reuse as flag
    if (tid == 0) {
        const int old = atomicAdd(a.cnt + tile, 1);
        *sflag = (old == SPLITS - 1) ? 1 : 0;
    }
    __syncthreads();
    if (*sflag == 0) return;
    __threadfence();                         // acquire: partials now visible

    // ---- last arrival: sum partials (fixed order) + gumbel epilogue ----
    const float* const base = a.part + (size_t)tile * SPLITS * (BM * BN);
    const int row   = tid >> 3;              // 32 rows, 8 threads/row
    const int grow  = bm + row;
    const int cbase = tid & 7;
    const int NV    = a.NV;
    float s = 0.f;
#pragma unroll
    for (int c = 0; c < 16; ++c) {
        const int col = cbase + c * 8;
        float v = a.bias[col];
#pragma unroll
        for (int sp = 0; sp < SPLITS; ++sp)
            v += base[sp * (BM * BN) + row * BN + col];
        if (col < NV) {
            const size_t idx = (size_t)grow * NV + col;
            const float g0 = a.g[2 * idx + 0];
            const float g1 = a.g[2 * idx + 1];
            const float m = ((v + g0) > (g1 - v)) ? 1.f : 0.f;
            a.out_mask[idx] = m;
            s += m;
        }
    }
    s += __shfl_xor(s, 1, 64);
    s += __shfl_xor(s, 2, 64);
    s += __shfl_xor(s, 4, 64);
    if ((tid & 7) == 0) {
        a.out_n[grow] = s;
        if (a.ws_n) a.ws_n[grow] = (int)s;
    }
}

// ---------------------------------------------------------------------------
// prep_all: block-range dispatch. Activation splits, weight transpose+splits
// (W2h padded to 128 rows), edge_index, split-K counter zeroing.
// ---------------------------------------------------------------------------
struct PrepArgs {
    const float *ph, *hh, *W1p, *W2p, *W1h, *W2h;
    bf16_t *pA_hi, *pA_lo, *hA_hi, *hA_lo;
    bf16_t *W1pT_hi, *W1pT_lo, *W2pT_hi, *W2pT_lo;
    bf16_t *W1hT_hi, *W1hT_lo, *W2hT_hi, *W2hT_lo;
    float *out_ei; int *ws_jj; int *ws_cnt;
};

__device__ __forceinline__ void split4(const float* x, bf16_t* hi, bf16_t* lo, int i) {
    float4 v = ((const float4*)x)[i];
    float vv[4] = {v.x, v.y, v.z, v.w};
    bf16x4 h, l;
#pragma unroll
    for (int r = 0; r < 4; ++r) {
        bf16_t hh = (bf16_t)vv[r];
        h[r] = hh;
        l[r] = (bf16_t)(vv[r] - (float)hh);
    }
    ((bf16x4*)hi)[i] = h;
    ((bf16x4*)lo)[i] = l;
}

__device__ __forceinline__ void tsplit(
    const float* W, bf16_t* Thi, bf16_t* Tlo, int K, int N,
    int t, int nx, float (*sh)[33], int tid)
{
    const int n0 = (t % nx) * 32, k0 = (t / nx) * 32;
    const int tx = tid & 31, ty = tid >> 5;
    for (int r = ty; r < 32; r += 8) {
        const int n = n0 + tx;
        sh[r][tx] = (n < N) ? W[(size_t)(k0 + r) * N + n] : 0.f;
    }
    __syncthreads();
    for (int r = ty; r < 32; r += 8) {
        const float x = sh[tx][r];     // = W[k0+tx][n0+r]
        bf16_t h = (bf16_t)x;
        bf16_t l = (bf16_t)(x - (float)h);
        const size_t off = (size_t)(n0 + r) * K + k0 + tx;
        Thi[off] = h;
        Tlo[off] = l;
    }
}

__device__ __forceinline__ int tri_off(int i) { return (i * (255 - i)) >> 1; }

// ranges: p-split 4096 | h-split 2048 | W1p 1024 | W2p 128 | W1h 256 |
//         W2h(pad128) 64 | edge_idx 32 | cnt-zero 1  => 7649 blocks
__global__ __launch_bounds__(256) void prep_all(PrepArgs a)
{
    __shared__ float sh[32][33];
    const int bid = blockIdx.x;
    const int tid = threadIdx.x;

    if (bid < 4096) {
        split4(a.ph, a.pA_hi, a.pA_lo, bid * 256 + tid);
    } else if (bid < 6144) {
        split4(a.hh, a.hA_hi, a.hA_lo, (bid - 4096) * 256 + tid);
    } else if (bid < 7168) {
        tsplit(a.W1p, a.W1pT_hi, a.W1pT_lo, P_HID, P_HID, bid - 6144, 32, sh, tid);
    } else if (bid < 7296) {
        tsplit(a.W2p, a.W2pT_hi, a.W2pT_lo, P_HID, MAX_P, bid - 7168, 4, sh, tid);
    } else if (bid < 7552) {
        tsplit(a.W1h, a.W1hT_hi, a.W1hT_lo, H_HID, H_HID, bid - 7296, 16, sh, tid);
    } else if (bid < 7616) {
        tsplit(a.W2h, a.W2hT_hi, a.W2hT_lo, H_HID, MAX_HE, bid - 7552, 4, sh, tid);
    } else if (bid < 7648) {
        const int e = (bid - 7616) * 256 + tid;
        if (e < E_MAX) {
            int i = (int)((255.0 - sqrt(65025.0 - 8.0 * (double)e)) * 0.5);
            if (i < 0) i = 0;
            if (i > 126) i = 126;
            while (i > 0 && tri_off(i) > e) --i;
            while (i < 126 && tri_off(i + 1) <= e) ++i;
            const int j = i + 1 + (e - tri_off(i));
            a.out_ei[e] = (float)i;
            a.out_ei[E_MAX + e] = (float)j;
            a.ws_jj[e] = j;
        }
    } else {
        a.ws_cnt[tid] = 0;                 // 256 split-K arrival counters
    }
}

// ---------------------------------------------------------------------------
// edge_valid[b,e] = jj[e] < n_particles[b]; float4-wide, nontemporal stores
// (write-once 133 MB stream — keep it out of L2/LLC). Uses clang ext-vector
// types (HIP_vector_type float4 is rejected by __builtin_nontemporal_store).
// ---------------------------------------------------------------------------
__global__ __launch_bounds__(256) void edge_valid_kernel(
    const int* __restrict__ ws_jj, const int* __restrict__ ws_n,
    float* __restrict__ out)
{
    const int b   = blockIdx.x >> 1;
    const int seg = blockIdx.x & 1;
    const int n   = ws_n[b];
    const int base = seg * (E_MAX4 / 2);                 // 1016
    float* const orow = out + (size_t)b * E_MAX;
#pragma unroll
    for (int it = 0; it < 4; ++it) {
        const int q = base + it * 256 + threadIdx.x;
        if (q < base + E_MAX4 / 2) {
            const i32x4 j4 = ((const i32x4*)ws_jj)[q];
            f32x4 v;
            v.x = (j4.x < n) ? 1.f : 0.f;
            v.y = (j4.y < n) ? 1.f : 0.f;
            v.z = (j4.z < n) ? 1.f : 0.f;
            v.w = (j4.w < n) ? 1.f : 0.f;
            __builtin_nontemporal_store(v, &((f32x4*)orow)[q]);
        }
    }
}

// ---------------------------------------------------------------------------
extern "C" void kernel_launch(void* const* d_in, const int* in_sizes, int n_in,
                              void* d_out, int out_size, void* d_ws, size_t ws_size,
                              hipStream_t stream)
{
    const float* particle_h  = (const float*)d_in[0];
    const float* hyperedge_h = (const float*)d_in[2];
    const float* g_p  = (const float*)d_in[3];
    const float* g_h  = (const float*)d_in[4];
    const float* W1_p = (const float*)d_in[5];
    const float* b1_p = (const float*)d_in[6];
    const float* W2_p = (const float*)d_in[7];
    const float* b2_p = (const float*)d_in[8];
    const float* W1_h = (const float*)d_in[9];
    const float* b1_h = (const float*)d_in[10];
    const float* W2_h = (const float*)d_in[11];
    const float* b2_h = (const float*)d_in[12];

    float* out = (float*)d_out;
    float* out_pmask = out;                                   // 4096*128
    float* out_np    = out_pmask + (size_t)B_SZ * MAX_P;      // 4096
    float* out_ei    = out_np + B_SZ;                         // 2*8128
    float* out_ev    = out_ei + 2 * E_MAX;                    // 4096*8128
    float* out_hmask = out_ev + (size_t)B_SZ * E_MAX;         // 4096*42
    float* out_nh    = out_hmask + (size_t)B_SZ * MAX_HE;     // 4096

    char* w = (char*)d_ws;
    bf16_t* pA_hi   = (bf16_t*)w;  w += (size_t)B_SZ * P_HID * 2;
    bf16_t* pA_lo   = (bf16_t*)w;  w += (size_t)B_SZ * P_HID * 2;
    bf16_t* hA_hi   = (bf16_t*)w;  w += (size_t)B_SZ * H_HID * 2;
    bf16_t* hA_lo   = (bf16_t*)w;  w += (size_t)B_SZ * H_HID * 2;
    bf16_t* hidp_hi = (bf16_t*)w;  w += (size_t)B_SZ * P_HID * 2;
    bf16_t* hidp_lo = (bf16_t*)w;  w += (size_t)B_SZ * P_HID * 2;
    bf16_t* hidh_hi = (bf16_t*)w;  w += (size_t)B_SZ * H_HID * 2;
    bf16_t* hidh_lo = (bf16_t*)w;  w += (size_t)B_SZ * H_HID * 2;
    bf16_t* W1pT_hi = (bf16_t*)w;  w += (size_t)P_HID * P_HID * 2;
    bf16_t* W1pT_lo = (bf16_t*)w;  w += (size_t)P_HID * P_HID * 2;
    bf16_t* W2pT_hi = (bf16_t*)w;  w += (size_t)MAX_P * P_HID * 2;
    bf16_t* W2pT_lo = (bf16_t*)w;  w += (size_t)MAX_P * P_HID * 2;
    bf16_t* W1hT_hi = (bf16_t*)w;  w += (size_t)H_HID * H_HID * 2;
    bf16_t* W1hT_lo = (bf16_t*)w;  w += (size_t)H_HID * H_HID * 2;
    bf16_t* W2hT_hi = (bf16_t*)w;  w += (size_t)HE_PAD * H_HID * 2;
    bf16_t* W2hT_lo = (bf16_t*)w;  w += (size_t)HE_PAD * H_HID * 2;
    int*    ws_np   = (int*)w;     w += B_SZ * 4;
    int*    ws_jj   = (int*)w;     w += E_MAX * 4;
    int*    ws_cnt  = (int*)w;     w += 256 * 4;

    // split-K partials alias the pA planes (16 MB, dead after gemm<0>):
    // [256 tiles][4 splits][32][128] f32 = 16 MB exactly.
    float* part_base = (float*)pA_hi;

    // ---- 1: fused prep ----
    PrepArgs pa;
    pa.ph = particle_h; pa.hh = hyperedge_h;
    pa.W1p = W1_p; pa.W2p = W2_p; pa.W1h = W1_h; pa.W2h = W2_h;
    pa.pA_hi = pA_hi; pa.pA_lo = pA_lo; pa.hA_hi = hA_hi; pa.hA_lo = hA_lo;
    pa.W1pT_hi = W1pT_hi; pa.W1pT_lo = W1pT_lo;
    pa.W2pT_hi = W2pT_hi; pa.W2pT_lo = W2pT_lo;
    pa.W1hT_hi = W1hT_hi; pa.W1hT_lo = W1hT_lo;
    pa.W2hT_hi = W2hT_hi; pa.W2hT_lo = W2hT_lo;
    pa.out_ei = out_ei; pa.ws_jj = ws_jj; pa.ws_cnt = ws_cnt;
    prep_all<<<7649, 256, 0, stream>>>(pa);

    // ---- 2: packed hidden GEMMs (R4-proven: BM=64, 512+256 blocks) ----
    {
        GemmP P = {}, H = {};
        P.Ahi = pA_hi;  P.Alo = pA_lo;  P.BThi = W1pT_hi; P.BTlo = W1pT_lo;
        P.bias = b1_p;  P.Chi = hidp_hi; P.Clo = hidp_lo;
        P.N = P_HID; P.K = P_HID; P.nx = P_HID / 128;         // 8 -> 512 blocks
        H.Ahi = hA_hi;  H.Alo = hA_lo;  H.BThi = W1hT_hi; H.BTlo = W1hT_lo;
        H.bias = b1_h;  H.Chi = hidh_hi; H.Clo = hidh_lo;
        H.N = H_HID; H.K = H_HID; H.nx = H_HID / 128;         // 4 -> 256 blocks
        const int pB = (B_SZ / 64) * P.nx;                    // 512
        const int hB = (B_SZ / 64) * H.nx;                    // 256
        gemm_pack<0, 64><<<pB + hB, 256, 0, stream>>>(P, H, pB);
    }

    // ---- 3: split-K x4 logit GEMMs + fused gumbel mask/count ----
    {
        GemmSK P = {}, H = {};
        P.Ahi = hidp_hi; P.Alo = hidp_lo; P.BThi = W2pT_hi; P.BTlo = W2pT_lo;
        P.bias = b2_p; P.g = g_p; P.out_mask = out_pmask; P.out_n = out_np;
        P.ws_n = ws_np; P.part = part_base; P.cnt = ws_cnt;
        P.K = P_HID; P.NV = MAX_P;
        H.Ahi = hidh_hi; H.Alo = hidh_lo; H.BThi = W2hT_hi; H.BTlo = W2hT_lo;
        H.bias = b2_h; H.g = g_h; H.out_mask = out_hmask; H.out_n = out_nh;
        H.ws_n = nullptr; H.part = part_base + (size_t)128 * 4 * 32 * 128;
        H.cnt = ws_cnt + 128; H.K = H_HID; H.NV = MAX_HE;
        const int pB = (B_SZ / 32) * 4;                       // 512
        const int hB = (B_SZ / 32) * 4;                       // 512
        gemm_logit_sk<<<pB + hB, 256, 0, stream>>>(P, H, pB);
    }

    // ---- 4: edge_valid ----
    edge_valid_kernel<<<2 * B_SZ, 256, 0, stream>>>(ws_jj, ws_np, out_ev);
}

// Round 7
// 261.583 us; speedup vs baseline: 1.7283x; 1.7283x over previous
//
#include <hip/hip_runtime.h>
#include <hip/hip_bf16.h>
#include <math.h>

typedef __bf16 bf16_t;
typedef bf16_t bf16x8 __attribute__((ext_vector_type(8)));
typedef bf16_t bf16x4 __attribute__((ext_vector_type(4)));
typedef float f32x4 __attribute__((ext_vector_type(4)));
typedef int i32x4 __attribute__((ext_vector_type(4)));
typedef unsigned int u32;

#define B_SZ 4096
#define P_HID 1024
#define H_HID 512
#define MAX_P 128
#define MAX_HE 42
#define HE_PAD 128          // W2h BT padded to 128 rows so G2h shares G2p's shape
#define E_MAX 8128
#define E_MAX4 2032

// ---------------------------------------------------------------------------
__device__ __forceinline__ void async_cp16(const bf16_t* g, bf16_t* l) {
    __builtin_amdgcn_global_load_lds(
        (const __attribute__((address_space(1))) u32*)g,
        (__attribute__((address_space(3))) u32*)l, 16, 0, 0);
}

__device__ __forceinline__ float gelu_exact(float v) {
    return 0.5f * v * (1.f + erff(v * 0.70710678118654752f));
}

// ---------------------------------------------------------------------------
// gemm_pack: R4-proven structure (A/B anchor at 274.4 us — do not touch).
// Packed split-bf16 3-MFMA GEMM, 2-phase pipelined, BM=64, 4 waves 2x2,
// 48KB LDS -> 3 blocks/CU. (R5: BM=128 dropped to 2 blocks/CU, +16us.
// R6: per-block __threadfence in a fused split-K epilogue cost ~240us in
// L2 writeback/invalidate — cross-block visibility only at kernel edges.)
// ---------------------------------------------------------------------------
struct GemmP {
    const bf16_t *Ahi, *Alo, *BThi, *BTlo;
    const float* bias;
    bf16_t *Chi, *Clo;
    int N, K, nx;                 // nx = blocks along N
};

template<int BM>
__global__ __launch_bounds__(256, 3) void gemm_pack(GemmP P, GemmP H, int pBlocks)
{
    constexpr int BN = 128;
    constexpr int MT = BM / 32;
    constexpr int NT = 4;                  // wave covers 64 cols
    constexpr int OPS_A = BM / 16;
    constexpr int OPS_B = BN / 16;
    constexpr int NOPS = 2 * OPS_A + 2 * OPS_B;
    constexpr int TILE = NOPS * 16 * 32;

    __shared__ __align__(16) bf16_t smem[2 * TILE];

    const bool isP = (int)blockIdx.x < pBlocks;
    const GemmP& a = isP ? P : H;
    const int bid  = isP ? blockIdx.x : blockIdx.x - pBlocks;
    const int bn   = (bid % a.nx) * BN;
    const int bm   = (bid / a.nx) * BM;
    const int K    = a.K;

    const int tid  = threadIdx.x;
    const int lane = tid & 63;
    const int wid  = tid >> 6;
    const int wm   = wid & 1;
    const int wn   = wid >> 1;

    const int srow = lane >> 2;
    const int scol = (lane & 3) * 8;
    const int fr   = lane & 15;
    const int fq   = lane >> 4;

    f32x4 acc[MT][NT];
#pragma unroll
    for (int i = 0; i < MT; ++i)
#pragma unroll
        for (int j = 0; j < NT; ++j)
            acc[i][j] = (f32x4){0.f, 0.f, 0.f, 0.f};

    const bf16_t* const gA0 = a.Ahi  + (size_t)bm * K;
    const bf16_t* const gA1 = a.Alo  + (size_t)bm * K;
    const bf16_t* const gB0 = a.BThi + (size_t)bn * K;
    const bf16_t* const gB1 = a.BTlo + (size_t)bn * K;

    auto stage = [&](int buf, int kt) {
#pragma unroll
        for (int o = 0; o < NOPS; ++o) {
            if ((o & 3) != wid) continue;
            const bf16_t* gsrc;
            int q, sec;
            if (o < OPS_A)                  { q = o;                     gsrc = gA0; sec = 0; }
            else if (o < 2 * OPS_A)         { q = o - OPS_A;             gsrc = gA1; sec = BM * 32; }
            else if (o < 2 * OPS_A + OPS_B) { q = o - 2 * OPS_A;         gsrc = gB0; sec = 2 * BM * 32; }
            else                            { q = o - 2 * OPS_A - OPS_B; gsrc = gB1; sec = 2 * BM * 32 + BN * 32; }
            async_cp16(gsrc + (size_t)(q * 16 + srow) * K + kt + scol,
                       smem + buf * TILE + sec + q * 16 * 32);
        }
    };

    stage(0, 0);
    __syncthreads();
    int cur = 0;
    for (int kt = 0; kt < K; kt += 32) {
        if (kt + 32 < K) stage(cur ^ 1, kt + 32);   // issue next tile EARLY

        const bf16_t* const Tb = smem + cur * TILE;
        bf16x8 ah[MT], al[MT];
#pragma unroll
        for (int i = 0; i < MT; ++i) {
            const int row = wm * (BM / 2) + i * 16 + fr;
            ah[i] = *(const bf16x8*)(Tb + row * 32 + fq * 8);
            al[i] = *(const bf16x8*)(Tb + BM * 32 + row * 32 + fq * 8);
        }
#pragma unroll
        for (int j = 0; j < NT; ++j) {
            const int row = wn * 64 + j * 16 + fr;
            const bf16x8 bh = *(const bf16x8*)(Tb + 2 * BM * 32 + row * 32 + fq * 8);
            const bf16x8 bl = *(const bf16x8*)(Tb + 2 * BM * 32 + BN * 32 + row * 32 + fq * 8);
#pragma unroll
            for (int i = 0; i < MT; ++i) {
                acc[i][j] = __builtin_amdgcn_mfma_f32_16x16x32_bf16(ah[i], bh, acc[i][j], 0, 0, 0);
                acc[i][j] = __builtin_amdgcn_mfma_f32_16x16x32_bf16(ah[i], bl, acc[i][j], 0, 0, 0);
                acc[i][j] = __builtin_amdgcn_mfma_f32_16x16x32_bf16(al[i], bh, acc[i][j], 0, 0, 0);
            }
        }
        __syncthreads();
        cur ^= 1;
    }

    // ---- epilogue ----  C/D layout: col = lane&15, row = (lane>>4)*4 + reg
#pragma unroll
    for (int i = 0; i < MT; ++i)
#pragma unroll
        for (int j = 0; j < NT; ++j) {
            const int col  = bn + wn * 64 + j * 16 + fr;
            const int row0 = bm + wm * (BM / 2) + i * 16 + fq * 4;
            const float bj = a.bias[col];
#pragma unroll
            for (int r = 0; r < 4; ++r) {
                float v = gelu_exact(acc[i][j][r] + bj);
                bf16_t h = (bf16_t)v;
                bf16_t l = (bf16_t)(v - (float)h);
                const size_t off = (size_t)(row0 + r) * a.N + col;
                a.Chi[off] = h;
                a.Clo[off] = l;
            }
        }
}

// ---------------------------------------------------------------------------
// gemm_logit_part: split-K x4 logit GEMM, PARTIALS ONLY (no fences/atomics —
// cross-block visibility comes from the kernel boundary; R6 lesson).
// 1024 blocks, 40KB LDS -> 4 blocks/CU (old fused gemm<1> had 1 block/CU).
// Each block computes K/4 of one 32x128 tile -> f32 partial in workspace.
// ---------------------------------------------------------------------------
struct PartP {
    const bf16_t *Ahi, *Alo, *BThi, *BTlo;
    float* part;               // [tiles][4][32][128] f32
    int K;
};

__global__ __launch_bounds__(256, 4) void gemm_logit_part(PartP P, PartP H, int pBlocks)
{
    constexpr int SPLITS = 4;
    constexpr int BM = 32, BN = 128, NT = 4;
    constexpr int OPS_A = BM / 16;                 // 2 per plane
    constexpr int OPS_B = BN / 16;                 // 8 per plane
    constexpr int NOPS  = 2 * OPS_A + 2 * OPS_B;   // 20
    constexpr int TILE  = NOPS * 16 * 32;          // 20 KB

    __shared__ __align__(16) bf16_t smem[2 * TILE];   // 40 KB

    const bool isP = (int)blockIdx.x < pBlocks;
    const PartP& a = isP ? P : H;
    const int bid   = isP ? blockIdx.x : blockIdx.x - pBlocks;
    const int tile  = bid >> 2;
    const int split = bid & (SPLITS - 1);
    const int bm    = tile * BM;
    const int K     = a.K;
    const int Ksub  = K / SPLITS;
    const int k0    = split * Ksub;

    const int tid  = threadIdx.x;
    const int lane = tid & 63;
    const int wid  = tid >> 6;
    const int wm   = wid & 1;              // 16-row half
    const int wn   = wid >> 1;             // 64-col half

    const int srow = lane >> 2;
    const int scol = (lane & 3) * 8;
    const int fr   = lane & 15;
    const int fq   = lane >> 4;

    f32x4 acc[NT];
#pragma unroll
    for (int j = 0; j < NT; ++j) acc[j] = (f32x4){0.f, 0.f, 0.f, 0.f};

    const bf16_t* const gA0 = a.Ahi  + (size_t)bm * K + k0;
    const bf16_t* const gA1 = a.Alo  + (size_t)bm * K + k0;
    const bf16_t* const gB0 = a.BThi + k0;             // bn == 0
    const bf16_t* const gB1 = a.BTlo + k0;

    auto stage = [&](int buf, int kt) {
#pragma unroll
        for (int o = 0; o < NOPS; ++o) {
            if ((o & 3) != wid) continue;
            const bf16_t* gsrc;
            int q, sec;
            if (o < OPS_A)                  { q = o;                     gsrc = gA0; sec = 0; }
            else if (o < 2 * OPS_A)         { q = o - OPS_A;             gsrc = gA1; sec = BM * 32; }
            else if (o < 2 * OPS_A + OPS_B) { q = o - 2 * OPS_A;         gsrc = gB0; sec = 2 * BM * 32; }
            else                            { q = o - 2 * OPS_A - OPS_B; gsrc = gB1; sec = 2 * BM * 32 + BN * 32; }
            async_cp16(gsrc + (size_t)(q * 16 + srow) * K + kt + scol,
                       smem + buf * TILE + sec + q * 16 * 32);
        }
    };

    stage(0, 0);
    __syncthreads();
    int cur = 0;
    for (int kt = 0; kt < Ksub; kt += 32) {
        if (kt + 32 < Ksub) stage(cur ^ 1, kt + 32);

        const bf16_t* const Tb = smem + cur * TILE;
        const int arow = wm * 16 + fr;
        const bf16x8 ah = *(const bf16x8*)(Tb + arow * 32 + fq * 8);
        const bf16x8 al = *(const bf16x8*)(Tb + BM * 32 + arow * 32 + fq * 8);
#pragma unroll
        for (int j = 0; j < NT; ++j) {
            const int brow = wn * 64 + j * 16 + fr;
            const bf16x8 bh = *(const bf16x8*)(Tb + 2 * BM * 32 + brow * 32 + fq * 8);
            const bf16x8 bl = *(const bf16x8*)(Tb + 2 * BM * 32 + BN * 32 + brow * 32 + fq * 8);
            acc[j] = __builtin_amdgcn_mfma_f32_16x16x32_bf16(ah, bh, acc[j], 0, 0, 0);
            acc[j] = __builtin_amdgcn_mfma_f32_16x16x32_bf16(ah, bl, acc[j], 0, 0, 0);
            acc[j] = __builtin_amdgcn_mfma_f32_16x16x32_bf16(al, bh, acc[j], 0, 0, 0);
        }
        __syncthreads();
        cur ^= 1;
    }

    // write partial tile (row-major f32); visibility via kernel boundary
    float* const pt = a.part + ((size_t)tile * SPLITS + split) * (BM * BN);
#pragma unroll
    for (int j = 0; j < NT; ++j)
#pragma unroll
        for (int r = 0; r < 4; ++r) {
            const int row_l = wm * 16 + fq * 4 + r;
            const int col   = wn * 64 + j * 16 + fr;
            pt[row_l * BN + col] = acc[j][r];
        }
}

// ---------------------------------------------------------------------------
// logit_reduce: sum 4 partials in FIXED order (deterministic) + bias +
// gumbel-hard mask + per-row count. 16 rows/block -> 512 blocks (2/CU).
// Coalesced f32x4 partial reads (32 lanes cover all 128 cols).
// ---------------------------------------------------------------------------
struct RedP {
    const float *part, *bias, *g;
    float *out_mask, *out_n;
    int *ws_n;                 // optional
    int NV;
};

__global__ __launch_bounds__(256) void logit_reduce(RedP P, RedP H, int pBlocks)
{
    constexpr int RB = 16;                  // rows per block
    const bool isP = (int)blockIdx.x < pBlocks;
    const RedP& a = isP ? P : H;
    const int blk  = isP ? blockIdx.x : blockIdx.x - pBlocks;
    const int tile = blk >> 1;              // 32-row partial tile
    const int half = blk & 1;
    const int bm   = tile * 32 + half * RB;

    const int tid = threadIdx.x;
    const int c0  = (tid & 31) * 4;         // 4 consecutive cols
    const int r0  = tid >> 5;               // 0..7
    const int NV  = a.NV;
    const float* const base = a.part + (size_t)tile * 4 * 32 * 128;

    float s[2];
#pragma unroll
    for (int rr = 0; rr < 2; ++rr) {
        const int row_l = half * RB + rr * 8 + r0;   // row in 32-row tile
        f32x4 v = *(const f32x4*)(a.bias + c0);
#pragma unroll
        for (int sp = 0; sp < 4; ++sp)
            v += *(const f32x4*)(base + sp * 4096 + row_l * 128 + c0);
        const int grow = tile * 32 + row_l;
        float cnt = 0.f;
#pragma unroll
        for (int k = 0; k < 4; ++k) {
            const int col = c0 + k;
            if (col < NV) {
                const size_t idx = (size_t)grow * NV + col;
                const float g0 = a.g[2 * idx + 0];
                const float g1 = a.g[2 * idx + 1];
                const float m = ((v[k] + g0) > (g1 - v[k])) ? 1.f : 0.f;
                a.out_mask[idx] = m;
                cnt += m;
            }
        }
        s[rr] = cnt;
    }
#pragma unroll
    for (int rr = 0; rr < 2; ++rr) {
        float t = s[rr];
        t += __shfl_xor(t, 1, 32);
        t += __shfl_xor(t, 2, 32);
        t += __shfl_xor(t, 4, 32);
        t += __shfl_xor(t, 8, 32);
        t += __shfl_xor(t, 16, 32);
        if ((tid & 31) == 0) {
            const int grow = tile * 32 + half * RB + rr * 8 + r0;
            a.out_n[grow] = t;
            if (a.ws_n) a.ws_n[grow] = (int)t;
        }
    }
}

// ---------------------------------------------------------------------------
// prep_all: block-range dispatch. Activation splits, weight transpose+splits
// (W2h padded to 128 rows), edge_index.
// ---------------------------------------------------------------------------
struct PrepArgs {
    const float *ph, *hh, *W1p, *W2p, *W1h, *W2h;
    bf16_t *pA_hi, *pA_lo, *hA_hi, *hA_lo;
    bf16_t *W1pT_hi, *W1pT_lo, *W2pT_hi, *W2pT_lo;
    bf16_t *W1hT_hi, *W1hT_lo, *W2hT_hi, *W2hT_lo;
    float *out_ei; int *ws_jj;
};

__device__ __forceinline__ void split4(const float* x, bf16_t* hi, bf16_t* lo, int i) {
    float4 v = ((const float4*)x)[i];
    float vv[4] = {v.x, v.y, v.z, v.w};
    bf16x4 h, l;
#pragma unroll
    for (int r = 0; r < 4; ++r) {
        bf16_t hh = (bf16_t)vv[r];
        h[r] = hh;
        l[r] = (bf16_t)(vv[r] - (float)hh);
    }
    ((bf16x4*)hi)[i] = h;
    ((bf16x4*)lo)[i] = l;
}

__device__ __forceinline__ void tsplit(
    const float* W, bf16_t* Thi, bf16_t* Tlo, int K, int N,
    int t, int nx, float (*sh)[33], int tid)
{
    const int n0 = (t % nx) * 32, k0 = (t / nx) * 32;
    const int tx = tid & 31, ty = tid >> 5;
    for (int r = ty; r < 32; r += 8) {
        const int n = n0 + tx;
        sh[r][tx] = (n < N) ? W[(size_t)(k0 + r) * N + n] : 0.f;
    }
    __syncthreads();
    for (int r = ty; r < 32; r += 8) {
        const float x = sh[tx][r];     // = W[k0+tx][n0+r]
        bf16_t h = (bf16_t)x;
        bf16_t l = (bf16_t)(x - (float)h);
        const size_t off = (size_t)(n0 + r) * K + k0 + tx;
        Thi[off] = h;
        Tlo[off] = l;
    }
}

__device__ __forceinline__ int tri_off(int i) { return (i * (255 - i)) >> 1; }

// ranges: p-split 4096 | h-split 2048 | W1p 1024 | W2p 128 | W1h 256 |
//         W2h(pad128) 64 | edge_idx 32   => 7648 blocks
__global__ __launch_bounds__(256) void prep_all(PrepArgs a)
{
    __shared__ float sh[32][33];
    const int bid = blockIdx.x;
    const int tid = threadIdx.x;

    if (bid < 4096) {
        split4(a.ph, a.pA_hi, a.pA_lo, bid * 256 + tid);
    } else if (bid < 6144) {
        split4(a.hh, a.hA_hi, a.hA_lo, (bid - 4096) * 256 + tid);
    } else if (bid < 7168) {
        tsplit(a.W1p, a.W1pT_hi, a.W1pT_lo, P_HID, P_HID, bid - 6144, 32, sh, tid);
    } else if (bid < 7296) {
        tsplit(a.W2p, a.W2pT_hi, a.W2pT_lo, P_HID, MAX_P, bid - 7168, 4, sh, tid);
    } else if (bid < 7552) {
        tsplit(a.W1h, a.W1hT_hi, a.W1hT_lo, H_HID, H_HID, bid - 7296, 16, sh, tid);
    } else if (bid < 7616) {
        tsplit(a.W2h, a.W2hT_hi, a.W2hT_lo, H_HID, MAX_HE, bid - 7552, 4, sh, tid);
    } else {
        const int e = (bid - 7616) * 256 + tid;
        if (e < E_MAX) {
            int i = (int)((255.0 - sqrt(65025.0 - 8.0 * (double)e)) * 0.5);
            if (i < 0) i = 0;
            if (i > 126) i = 126;
            while (i > 0 && tri_off(i) > e) --i;
            while (i < 126 && tri_off(i + 1) <= e) ++i;
            const int j = i + 1 + (e - tri_off(i));
            a.out_ei[e] = (float)i;
            a.out_ei[E_MAX + e] = (float)j;
            a.ws_jj[e] = j;
        }
    }
}

// ---------------------------------------------------------------------------
// edge_valid[b,e] = jj[e] < n_particles[b]; float4-wide, nontemporal stores
// (write-once 133 MB stream — keep it out of L2/LLC).
// ---------------------------------------------------------------------------
__global__ __launch_bounds__(256) void edge_valid_kernel(
    const int* __restrict__ ws_jj, const int* __restrict__ ws_n,
    float* __restrict__ out)
{
    const int b   = blockIdx.x >> 1;
    const int seg = blockIdx.x & 1;
    const int n   = ws_n[b];
    const int base = seg * (E_MAX4 / 2);                 // 1016
    float* const orow = out + (size_t)b * E_MAX;
#pragma unroll
    for (int it = 0; it < 4; ++it) {
        const int q = base + it * 256 + threadIdx.x;
        if (q < base + E_MAX4 / 2) {
            const i32x4 j4 = ((const i32x4*)ws_jj)[q];
            f32x4 v;
            v.x = (j4.x < n) ? 1.f : 0.f;
            v.y = (j4.y < n) ? 1.f : 0.f;
            v.z = (j4.z < n) ? 1.f : 0.f;
            v.w = (j4.w < n) ? 1.f : 0.f;
            __builtin_nontemporal_store(v, &((f32x4*)orow)[q]);
        }
    }
}

// ---------------------------------------------------------------------------
extern "C" void kernel_launch(void* const* d_in, const int* in_sizes, int n_in,
                              void* d_out, int out_size, void* d_ws, size_t ws_size,
                              hipStream_t stream)
{
    const float* particle_h  = (const float*)d_in[0];
    const float* hyperedge_h = (const float*)d_in[2];
    const float* g_p  = (const float*)d_in[3];
    const float* g_h  = (const float*)d_in[4];
    const float* W1_p = (const float*)d_in[5];
    const float* b1_p = (const float*)d_in[6];
    const float* W2_p = (const float*)d_in[7];
    const float* b2_p = (const float*)d_in[8];
    const float* W1_h = (const float*)d_in[9];
    const float* b1_h = (const float*)d_in[10];
    const float* W2_h = (const float*)d_in[11];
    const float* b2_h = (const float*)d_in[12];

    float* out = (float*)d_out;
    float* out_pmask = out;                                   // 4096*128
    float* out_np    = out_pmask + (size_t)B_SZ * MAX_P;      // 4096
    float* out_ei    = out_np + B_SZ;                         // 2*8128
    float* out_ev    = out_ei + 2 * E_MAX;                    // 4096*8128
    float* out_hmask = out_ev + (size_t)B_SZ * E_MAX;         // 4096*42
    float* out_nh    = out_hmask + (size_t)B_SZ * MAX_HE;     // 4096

    char* w = (char*)d_ws;
    bf16_t* pA_hi   = (bf16_t*)w;  w += (size_t)B_SZ * P_HID * 2;
    bf16_t* pA_lo   = (bf16_t*)w;  w += (size_t)B_SZ * P_HID * 2;
    bf16_t* hA_hi   = (bf16_t*)w;  w += (size_t)B_SZ * H_HID * 2;
    bf16_t* hA_lo   = (bf16_t*)w;  w += (size_t)B_SZ * H_HID * 2;
    bf16_t* hidp_hi = (bf16_t*)w;  w += (size_t)B_SZ * P_HID * 2;
    bf16_t* hidp_lo = (bf16_t*)w;  w += (size_t)B_SZ * P_HID * 2;
    bf16_t* hidh_hi = (bf16_t*)w;  w += (size_t)B_SZ * H_HID * 2;
    bf16_t* hidh_lo = (bf16_t*)w;  w += (size_t)B_SZ * H_HID * 2;
    bf16_t* W1pT_hi = (bf16_t*)w;  w += (size_t)P_HID * P_HID * 2;
    bf16_t* W1pT_lo = (bf16_t*)w;  w += (size_t)P_HID * P_HID * 2;
    bf16_t* W2pT_hi = (bf16_t*)w;  w += (size_t)MAX_P * P_HID * 2;
    bf16_t* W2pT_lo = (bf16_t*)w;  w += (size_t)MAX_P * P_HID * 2;
    bf16_t* W1hT_hi = (bf16_t*)w;  w += (size_t)H_HID * H_HID * 2;
    bf16_t* W1hT_lo = (bf16_t*)w;  w += (size_t)H_HID * H_HID * 2;
    bf16_t* W2hT_hi = (bf16_t*)w;  w += (size_t)HE_PAD * H_HID * 2;
    bf16_t* W2hT_lo = (bf16_t*)w;  w += (size_t)HE_PAD * H_HID * 2;
    int*    ws_np   = (int*)w;     w += B_SZ * 4;
    int*    ws_jj   = (int*)w;     w += E_MAX * 4;

    // split-K partials alias the pA planes (16 MB, dead after gemm_pack):
    // P: [128 tiles][4][32][128] f32 = 8 MB, H: +8 MB.
    float* part_base = (float*)pA_hi;

    // ---- 1: fused prep ----
    PrepArgs pa;
    pa.ph = particle_h; pa.hh = hyperedge_h;
    pa.W1p = W1_p; pa.W2p = W2_p; pa.W1h = W1_h; pa.W2h = W2_h;
    pa.pA_hi = pA_hi; pa.pA_lo = pA_lo; pa.hA_hi = hA_hi; pa.hA_lo = hA_lo;
    pa.W1pT_hi = W1pT_hi; pa.W1pT_lo = W1pT_lo;
    pa.W2pT_hi = W2pT_hi; pa.W2pT_lo = W2pT_lo;
    pa.W1hT_hi = W1hT_hi; pa.W1hT_lo = W1hT_lo;
    pa.W2hT_hi = W2hT_hi; pa.W2hT_lo = W2hT_lo;
    pa.out_ei = out_ei; pa.ws_jj = ws_jj;
    prep_all<<<7648, 256, 0, stream>>>(pa);

    // ---- 2: packed hidden GEMMs (R4-proven: BM=64, 512+256 blocks) ----
    {
        GemmP P = {}, H = {};
        P.Ahi = pA_hi;  P.Alo = pA_lo;  P.BThi = W1pT_hi; P.BTlo = W1pT_lo;
        P.bias = b1_p;  P.Chi = hidp_hi; P.Clo = hidp_lo;
        P.N = P_HID; P.K = P_HID; P.nx = P_HID / 128;         // 8 -> 512 blocks
        H.Ahi = hA_hi;  H.Alo = hA_lo;  H.BThi = W1hT_hi; H.BTlo = W1hT_lo;
        H.bias = b1_h;  H.Chi = hidh_hi; H.Clo = hidh_lo;
        H.N = H_HID; H.K = H_HID; H.nx = H_HID / 128;         // 4 -> 256 blocks
        const int pB = (B_SZ / 64) * P.nx;                    // 512
        const int hB = (B_SZ / 64) * H.nx;                    // 256
        gemm_pack<64><<<pB + hB, 256, 0, stream>>>(P, H, pB);
    }

    // ---- 3a: split-K x4 logit GEMM partials (fence-free) ----
    {
        PartP P = {}, H = {};
        P.Ahi = hidp_hi; P.Alo = hidp_lo; P.BThi = W2pT_hi; P.BTlo = W2pT_lo;
        P.part = part_base; P.K = P_HID;
        H.Ahi = hidh_hi; H.Alo = hidh_lo; H.BThi = W2hT_hi; H.BTlo = W2hT_lo;
        H.part = part_base + (size_t)128 * 4 * 32 * 128; H.K = H_HID;
        const int pB = (B_SZ / 32) * 4;                       // 512
        const int hB = (B_SZ / 32) * 4;                       // 512
        gemm_logit_part<<<pB + hB, 256, 0, stream>>>(P, H, pB);
    }

    // ---- 3b: deterministic partial-sum + gumbel mask/count ----
    {
        RedP P = {}, H = {};
        P.part = part_base; P.bias = b2_p; P.g = g_p;
        P.out_mask = out_pmask; P.out_n = out_np; P.ws_n = ws_np; P.NV = MAX_P;
        H.part = part_base + (size_t)128 * 4 * 32 * 128; H.bias = b2_h; H.g = g_h;
        H.out_mask = out_hmask; H.out_n = out_nh; H.ws_n = nullptr; H.NV = MAX_HE;
        const int pB = B_SZ / 16;                             // 256
        const int hB = B_SZ / 16;                             // 256
        logit_reduce<<<pB + hB, 256, 0, stream>>>(P, H, pB);
    }

    // ---- 4: edge_valid ----
    edge_valid_kernel<<<2 * B_SZ, 256, 0, stream>>>(ws_jj, ws_np, out_ev);
}

// Round 8
// 258.126 us; speedup vs baseline: 1.7514x; 1.0134x over previous
//
#include <hip/hip_runtime.h>
#include <hip/hip_bf16.h>
#include <math.h>

typedef __bf16 bf16_t;
typedef bf16_t bf16x8 __attribute__((ext_vector_type(8)));
typedef bf16_t bf16x4 __attribute__((ext_vector_type(4)));
typedef float f32x4 __attribute__((ext_vector_type(4)));
typedef int i32x4 __attribute__((ext_vector_type(4)));
typedef unsigned int u32;

#define B_SZ 4096
#define P_HID 1024
#define H_HID 512
#define MAX_P 128
#define MAX_HE 42
#define HE_PAD 128          // W2h BT padded to 128 rows so G2h shares G2p's shape
#define E_MAX 8128
#define E_MAX4 2032

// ---------------------------------------------------------------------------
__device__ __forceinline__ void async_cp16(const bf16_t* g, bf16_t* l) {
    __builtin_amdgcn_global_load_lds(
        (const __attribute__((address_space(1))) u32*)g,
        (__attribute__((address_space(3))) u32*)l, 16, 0, 0);
}

__device__ __forceinline__ float gelu_exact(float v) {
    return 0.5f * v * (1.f + erff(v * 0.70710678118654752f));
}

// ---------------------------------------------------------------------------
// gemm_pack: R4-proven structure + chunked XCD swizzle.
// Packed split-bf16 3-MFMA GEMM, 2-phase pipelined, BM=64, 4 waves 2x2,
// 48KB LDS -> 3 blocks/CU. (R5: BM=128 @2 blocks/CU regressed +16us.
// R6: per-block __threadfence cost ~240us — visibility only at kernel edges.)
// Swizzle: XCD = blockIdx%8 (round-robin); remap bid=(bid&7)*(nb/8)+(bid>>3)
// so each XCD gets a contiguous tile chunk: per-XCD working set 6MB (8 A-
// panels + full B) instead of full-A 16MB -> L2-miss traffic ~132MB -> ~48MB.
// ---------------------------------------------------------------------------
struct GemmP {
    const bf16_t *Ahi, *Alo, *BThi, *BTlo;
    const float* bias;
    bf16_t *Chi, *Clo;
    int N, K, nx;                 // nx = blocks along N
};

template<int BM>
__global__ __launch_bounds__(256, 3) void gemm_pack(GemmP P, GemmP H, int pBlocks)
{
    constexpr int BN = 128;
    constexpr int MT = BM / 32;
    constexpr int NT = 4;                  // wave covers 64 cols
    constexpr int OPS_A = BM / 16;
    constexpr int OPS_B = BN / 16;
    constexpr int NOPS = 2 * OPS_A + 2 * OPS_B;
    constexpr int TILE = NOPS * 16 * 32;

    __shared__ __align__(16) bf16_t smem[2 * TILE];

    const bool isP = (int)blockIdx.x < pBlocks;
    const GemmP& a = isP ? P : H;
    int bid = isP ? blockIdx.x : blockIdx.x - pBlocks;
    // chunked XCD swizzle (both ranges divisible by 8; bijective)
    {
        const int nb = isP ? pBlocks : (int)gridDim.x - pBlocks;
        bid = (bid & 7) * (nb >> 3) + (bid >> 3);
    }
    const int bn   = (bid % a.nx) * BN;
    const int bm   = (bid / a.nx) * BM;
    const int K    = a.K;

    const int tid  = threadIdx.x;
    const int lane = tid & 63;
    const int wid  = tid >> 6;
    const int wm   = wid & 1;
    const int wn   = wid >> 1;

    const int srow = lane >> 2;
    const int scol = (lane & 3) * 8;
    const int fr   = lane & 15;
    const int fq   = lane >> 4;

    f32x4 acc[MT][NT];
#pragma unroll
    for (int i = 0; i < MT; ++i)
#pragma unroll
        for (int j = 0; j < NT; ++j)
            acc[i][j] = (f32x4){0.f, 0.f, 0.f, 0.f};

    const bf16_t* const gA0 = a.Ahi  + (size_t)bm * K;
    const bf16_t* const gA1 = a.Alo  + (size_t)bm * K;
    const bf16_t* const gB0 = a.BThi + (size_t)bn * K;
    const bf16_t* const gB1 = a.BTlo + (size_t)bn * K;

    auto stage = [&](int buf, int kt) {
#pragma unroll
        for (int o = 0; o < NOPS; ++o) {
            if ((o & 3) != wid) continue;
            const bf16_t* gsrc;
            int q, sec;
            if (o < OPS_A)                  { q = o;                     gsrc = gA0; sec = 0; }
            else if (o < 2 * OPS_A)         { q = o - OPS_A;             gsrc = gA1; sec = BM * 32; }
            else if (o < 2 * OPS_A + OPS_B) { q = o - 2 * OPS_A;         gsrc = gB0; sec = 2 * BM * 32; }
            else                            { q = o - 2 * OPS_A - OPS_B; gsrc = gB1; sec = 2 * BM * 32 + BN * 32; }
            async_cp16(gsrc + (size_t)(q * 16 + srow) * K + kt + scol,
                       smem + buf * TILE + sec + q * 16 * 32);
        }
    };

    stage(0, 0);
    __syncthreads();
    int cur = 0;
    for (int kt = 0; kt < K; kt += 32) {
        if (kt + 32 < K) stage(cur ^ 1, kt + 32);   // issue next tile EARLY

        const bf16_t* const Tb = smem + cur * TILE;
        bf16x8 ah[MT], al[MT];
#pragma unroll
        for (int i = 0; i < MT; ++i) {
            const int row = wm * (BM / 2) + i * 16 + fr;
            ah[i] = *(const bf16x8*)(Tb + row * 32 + fq * 8);
            al[i] = *(const bf16x8*)(Tb + BM * 32 + row * 32 + fq * 8);
        }
#pragma unroll
        for (int j = 0; j < NT; ++j) {
            const int row = wn * 64 + j * 16 + fr;
            const bf16x8 bh = *(const bf16x8*)(Tb + 2 * BM * 32 + row * 32 + fq * 8);
            const bf16x8 bl = *(const bf16x8*)(Tb + 2 * BM * 32 + BN * 32 + row * 32 + fq * 8);
#pragma unroll
            for (int i = 0; i < MT; ++i) {
                acc[i][j] = __builtin_amdgcn_mfma_f32_16x16x32_bf16(ah[i], bh, acc[i][j], 0, 0, 0);
                acc[i][j] = __builtin_amdgcn_mfma_f32_16x16x32_bf16(ah[i], bl, acc[i][j], 0, 0, 0);
                acc[i][j] = __builtin_amdgcn_mfma_f32_16x16x32_bf16(al[i], bh, acc[i][j], 0, 0, 0);
            }
        }
        __syncthreads();
        cur ^= 1;
    }

    // ---- epilogue ----  C/D layout: col = lane&15, row = (lane>>4)*4 + reg
#pragma unroll
    for (int i = 0; i < MT; ++i)
#pragma unroll
        for (int j = 0; j < NT; ++j) {
            const int col  = bn + wn * 64 + j * 16 + fr;
            const int row0 = bm + wm * (BM / 2) + i * 16 + fq * 4;
            const float bj = a.bias[col];
#pragma unroll
            for (int r = 0; r < 4; ++r) {
                float v = gelu_exact(acc[i][j][r] + bj);
                bf16_t h = (bf16_t)v;
                bf16_t l = (bf16_t)(v - (float)h);
                const size_t off = (size_t)(row0 + r) * a.N + col;
                a.Chi[off] = h;
                a.Clo[off] = l;
            }
        }
}

// ---------------------------------------------------------------------------
// gemm_logit_part: split-K x4 logit GEMM, PARTIALS ONLY (fence-free; R6
// lesson). 1024 blocks, 40KB LDS -> 4 blocks/CU. No cross-block A/B reuse
// worth swizzling (each A row read once; B is L2-resident everywhere).
// ---------------------------------------------------------------------------
struct PartP {
    const bf16_t *Ahi, *Alo, *BThi, *BTlo;
    float* part;               // [tiles][4][32][128] f32
    int K;
};

__global__ __launch_bounds__(256, 4) void gemm_logit_part(PartP P, PartP H, int pBlocks)
{
    constexpr int SPLITS = 4;
    constexpr int BM = 32, BN = 128, NT = 4;
    constexpr int OPS_A = BM / 16;                 // 2 per plane
    constexpr int OPS_B = BN / 16;                 // 8 per plane
    constexpr int NOPS  = 2 * OPS_A + 2 * OPS_B;   // 20
    constexpr int TILE  = NOPS * 16 * 32;          // 20 KB

    __shared__ __align__(16) bf16_t smem[2 * TILE];   // 40 KB

    const bool isP = (int)blockIdx.x < pBlocks;
    const PartP& a = isP ? P : H;
    const int bid   = isP ? blockIdx.x : blockIdx.x - pBlocks;
    const int tile  = bid >> 2;
    const int split = bid & (SPLITS - 1);
    const int bm    = tile * BM;
    const int K     = a.K;
    const int Ksub  = K / SPLITS;
    const int k0    = split * Ksub;

    const int tid  = threadIdx.x;
    const int lane = tid & 63;
    const int wid  = tid >> 6;
    const int wm   = wid & 1;              // 16-row half
    const int wn   = wid >> 1;             // 64-col half

    const int srow = lane >> 2;
    const int scol = (lane & 3) * 8;
    const int fr   = lane & 15;
    const int fq   = lane >> 4;

    f32x4 acc[NT];
#pragma unroll
    for (int j = 0; j < NT; ++j) acc[j] = (f32x4){0.f, 0.f, 0.f, 0.f};

    const bf16_t* const gA0 = a.Ahi  + (size_t)bm * K + k0;
    const bf16_t* const gA1 = a.Alo  + (size_t)bm * K + k0;
    const bf16_t* const gB0 = a.BThi + k0;             // bn == 0
    const bf16_t* const gB1 = a.BTlo + k0;

    auto stage = [&](int buf, int kt) {
#pragma unroll
        for (int o = 0; o < NOPS; ++o) {
            if ((o & 3) != wid) continue;
            const bf16_t* gsrc;
            int q, sec;
            if (o < OPS_A)                  { q = o;                     gsrc = gA0; sec = 0; }
            else if (o < 2 * OPS_A)         { q = o - OPS_A;             gsrc = gA1; sec = BM * 32; }
            else if (o < 2 * OPS_A + OPS_B) { q = o - 2 * OPS_A;         gsrc = gB0; sec = 2 * BM * 32; }
            else                            { q = o - 2 * OPS_A - OPS_B; gsrc = gB1; sec = 2 * BM * 32 + BN * 32; }
            async_cp16(gsrc + (size_t)(q * 16 + srow) * K + kt + scol,
                       smem + buf * TILE + sec + q * 16 * 32);
        }
    };

    stage(0, 0);
    __syncthreads();
    int cur = 0;
    for (int kt = 0; kt < Ksub; kt += 32) {
        if (kt + 32 < Ksub) stage(cur ^ 1, kt + 32);

        const bf16_t* const Tb = smem + cur * TILE;
        const int arow = wm * 16 + fr;
        const bf16x8 ah = *(const bf16x8*)(Tb + arow * 32 + fq * 8);
        const bf16x8 al = *(const bf16x8*)(Tb + BM * 32 + arow * 32 + fq * 8);
#pragma unroll
        for (int j = 0; j < NT; ++j) {
            const int brow = wn * 64 + j * 16 + fr;
            const bf16x8 bh = *(const bf16x8*)(Tb + 2 * BM * 32 + brow * 32 + fq * 8);
            const bf16x8 bl = *(const bf16x8*)(Tb + 2 * BM * 32 + BN * 32 + brow * 32 + fq * 8);
            acc[j] = __builtin_amdgcn_mfma_f32_16x16x32_bf16(ah, bh, acc[j], 0, 0, 0);
            acc[j] = __builtin_amdgcn_mfma_f32_16x16x32_bf16(ah, bl, acc[j], 0, 0, 0);
            acc[j] = __builtin_amdgcn_mfma_f32_16x16x32_bf16(al, bh, acc[j], 0, 0, 0);
        }
        __syncthreads();
        cur ^= 1;
    }

    // write partial tile (row-major f32); visibility via kernel boundary
    float* const pt = a.part + ((size_t)tile * SPLITS + split) * (BM * BN);
#pragma unroll
    for (int j = 0; j < NT; ++j)
#pragma unroll
        for (int r = 0; r < 4; ++r) {
            const int row_l = wm * 16 + fq * 4 + r;
            const int col   = wn * 64 + j * 16 + fr;
            pt[row_l * BN + col] = acc[j][r];
        }
}

// ---------------------------------------------------------------------------
// logit_reduce_ev: fixed-order partial sum + bias + gumbel mask/count, then
// (P branch) edge_valid rows written directly — the count never leaves the
// block, killing the ws_np round-trip and the separate 8192-block kernel.
// 4 rows/block: 1 warp per row for the reduce; all 256 threads stream the
// 4 x 8128-col ev rows with nontemporal f32x4 stores.
// ---------------------------------------------------------------------------
struct RedEV {
    const float *part, *bias, *g;
    float *out_mask, *out_n;
    const int* jj;             // null for H
    float* ev;                 // null for H
    int NV;
};

__global__ __launch_bounds__(256) void logit_reduce_ev(RedEV P, RedEV H, int pBlocks)
{
    __shared__ int sn[4];
    const bool isP = (int)blockIdx.x < pBlocks;
    const RedEV& a = isP ? P : H;
    const int blk  = isP ? blockIdx.x : blockIdx.x - pBlocks;
    const int tid  = threadIdx.x;
    const int wid  = tid >> 6;
    const int lane = tid & 63;

    // ---- phase 1: warp `wid` reduces row blk*4+wid (2 cols/lane) ----
    const int grow  = blk * 4 + wid;
    const int tile  = grow >> 5;
    const int row_l = grow & 31;
    const float* const base = a.part + ((size_t)tile * 4 * 32 + row_l) * 128;
    const int c0 = lane * 2;
    float v0 = a.bias[c0];
    float v1 = a.bias[c0 + 1];
#pragma unroll
    for (int sp = 0; sp < 4; ++sp) {       // FIXED order -> deterministic
        const float* p = base + sp * 4096;
        v0 += p[c0];
        v1 += p[c0 + 1];
    }
    const int NV = a.NV;
    float cnt = 0.f;
#pragma unroll
    for (int k = 0; k < 2; ++k) {
        const int col = c0 + k;
        const float v = k ? v1 : v0;
        if (col < NV) {
            const size_t idx = (size_t)grow * NV + col;
            const float g0 = a.g[2 * idx + 0];
            const float g1 = a.g[2 * idx + 1];
            const float m = ((v + g0) > (g1 - v)) ? 1.f : 0.f;
            a.out_mask[idx] = m;
            cnt += m;
        }
    }
    cnt += __shfl_xor(cnt, 1, 64);
    cnt += __shfl_xor(cnt, 2, 64);
    cnt += __shfl_xor(cnt, 4, 64);
    cnt += __shfl_xor(cnt, 8, 64);
    cnt += __shfl_xor(cnt, 16, 64);
    cnt += __shfl_xor(cnt, 32, 64);
    if (lane == 0) {
        a.out_n[grow] = cnt;
        sn[wid] = (int)cnt;
    }
    __syncthreads();

    // ---- phase 2 (P only): stream the 4 ev rows ----
    if (!a.ev) return;
#pragma unroll
    for (int rr = 0; rr < 4; ++rr) {
        const int n = sn[rr];
        float* const orow = a.ev + (size_t)(blk * 4 + rr) * E_MAX;
        for (int q = tid; q < E_MAX4; q += 256) {
            const i32x4 j4 = ((const i32x4*)a.jj)[q];
            f32x4 v;
            v.x = (j4.x < n) ? 1.f : 0.f;
            v.y = (j4.y < n) ? 1.f : 0.f;
            v.z = (j4.z < n) ? 1.f : 0.f;
            v.w = (j4.w < n) ? 1.f : 0.f;
            __builtin_nontemporal_store(v, &((f32x4*)orow)[q]);
        }
    }
}

// ---------------------------------------------------------------------------
// prep_all: block-range dispatch. Activation splits, weight transpose+splits
// (W2h padded to 128 rows), edge_index.
// ---------------------------------------------------------------------------
struct PrepArgs {
    const float *ph, *hh, *W1p, *W2p, *W1h, *W2h;
    bf16_t *pA_hi, *pA_lo, *hA_hi, *hA_lo;
    bf16_t *W1pT_hi, *W1pT_lo, *W2pT_hi, *W2pT_lo;
    bf16_t *W1hT_hi, *W1hT_lo, *W2hT_hi, *W2hT_lo;
    float *out_ei; int *ws_jj;
};

__device__ __forceinline__ void split4(const float* x, bf16_t* hi, bf16_t* lo, int i) {
    float4 v = ((const float4*)x)[i];
    float vv[4] = {v.x, v.y, v.z, v.w};
    bf16x4 h, l;
#pragma unroll
    for (int r = 0; r < 4; ++r) {
        bf16_t hh = (bf16_t)vv[r];
        h[r] = hh;
        l[r] = (bf16_t)(vv[r] - (float)hh);
    }
    ((bf16x4*)hi)[i] = h;
    ((bf16x4*)lo)[i] = l;
}

__device__ __forceinline__ void tsplit(
    const float* W, bf16_t* Thi, bf16_t* Tlo, int K, int N,
    int t, int nx, float (*sh)[33], int tid)
{
    const int n0 = (t % nx) * 32, k0 = (t / nx) * 32;
    const int tx = tid & 31, ty = tid >> 5;
    for (int r = ty; r < 32; r += 8) {
        const int n = n0 + tx;
        sh[r][tx] = (n < N) ? W[(size_t)(k0 + r) * N + n] : 0.f;
    }
    __syncthreads();
    for (int r = ty; r < 32; r += 8) {
        const float x = sh[tx][r];     // = W[k0+tx][n0+r]
        bf16_t h = (bf16_t)x;
        bf16_t l = (bf16_t)(x - (float)h);
        const size_t off = (size_t)(n0 + r) * K + k0 + tx;
        Thi[off] = h;
        Tlo[off] = l;
    }
}

__device__ __forceinline__ int tri_off(int i) { return (i * (255 - i)) >> 1; }

// ranges: p-split 4096 | h-split 2048 | W1p 1024 | W2p 128 | W1h 256 |
//         W2h(pad128) 64 | edge_idx 32   => 7648 blocks
__global__ __launch_bounds__(256) void prep_all(PrepArgs a)
{
    __shared__ float sh[32][33];
    const int bid = blockIdx.x;
    const int tid = threadIdx.x;

    if (bid < 4096) {
        split4(a.ph, a.pA_hi, a.pA_lo, bid * 256 + tid);
    } else if (bid < 6144) {
        split4(a.hh, a.hA_hi, a.hA_lo, (bid - 4096) * 256 + tid);
    } else if (bid < 7168) {
        tsplit(a.W1p, a.W1pT_hi, a.W1pT_lo, P_HID, P_HID, bid - 6144, 32, sh, tid);
    } else if (bid < 7296) {
        tsplit(a.W2p, a.W2pT_hi, a.W2pT_lo, P_HID, MAX_P, bid - 7168, 4, sh, tid);
    } else if (bid < 7552) {
        tsplit(a.W1h, a.W1hT_hi, a.W1hT_lo, H_HID, H_HID, bid - 7296, 16, sh, tid);
    } else if (bid < 7616) {
        tsplit(a.W2h, a.W2hT_hi, a.W2hT_lo, H_HID, MAX_HE, bid - 7552, 4, sh, tid);
    } else {
        const int e = (bid - 7616) * 256 + tid;
        if (e < E_MAX) {
            int i = (int)((255.0 - sqrt(65025.0 - 8.0 * (double)e)) * 0.5);
            if (i < 0) i = 0;
            if (i > 126) i = 126;
            while (i > 0 && tri_off(i) > e) --i;
            while (i < 126 && tri_off(i + 1) <= e) ++i;
            const int j = i + 1 + (e - tri_off(i));
            a.out_ei[e] = (float)i;
            a.out_ei[E_MAX + e] = (float)j;
            a.ws_jj[e] = j;
        }
    }
}

// ---------------------------------------------------------------------------
extern "C" void kernel_launch(void* const* d_in, const int* in_sizes, int n_in,
                              void* d_out, int out_size, void* d_ws, size_t ws_size,
                              hipStream_t stream)
{
    const float* particle_h  = (const float*)d_in[0];
    const float* hyperedge_h = (const float*)d_in[2];
    const float* g_p  = (const float*)d_in[3];
    const float* g_h  = (const float*)d_in[4];
    const float* W1_p = (const float*)d_in[5];
    const float* b1_p = (const float*)d_in[6];
    const float* W2_p = (const float*)d_in[7];
    const float* b2_p = (const float*)d_in[8];
    const float* W1_h = (const float*)d_in[9];
    const float* b1_h = (const float*)d_in[10];
    const float* W2_h = (const float*)d_in[11];
    const float* b2_h = (const float*)d_in[12];

    float* out = (float*)d_out;
    float* out_pmask = out;                                   // 4096*128
    float* out_np    = out_pmask + (size_t)B_SZ * MAX_P;      // 4096
    float* out_ei    = out_np + B_SZ;                         // 2*8128
    float* out_ev    = out_ei + 2 * E_MAX;                    // 4096*8128
    float* out_hmask = out_ev + (size_t)B_SZ * E_MAX;         // 4096*42
    float* out_nh    = out_hmask + (size_t)B_SZ * MAX_HE;     // 4096

    char* w = (char*)d_ws;
    bf16_t* pA_hi   = (bf16_t*)w;  w += (size_t)B_SZ * P_HID * 2;
    bf16_t* pA_lo   = (bf16_t*)w;  w += (size_t)B_SZ * P_HID * 2;
    bf16_t* hA_hi   = (bf16_t*)w;  w += (size_t)B_SZ * H_HID * 2;
    bf16_t* hA_lo   = (bf16_t*)w;  w += (size_t)B_SZ * H_HID * 2;
    bf16_t* hidp_hi = (bf16_t*)w;  w += (size_t)B_SZ * P_HID * 2;
    bf16_t* hidp_lo = (bf16_t*)w;  w += (size_t)B_SZ * P_HID * 2;
    bf16_t* hidh_hi = (bf16_t*)w;  w += (size_t)B_SZ * H_HID * 2;
    bf16_t* hidh_lo = (bf16_t*)w;  w += (size_t)B_SZ * H_HID * 2;
    bf16_t* W1pT_hi = (bf16_t*)w;  w += (size_t)P_HID * P_HID * 2;
    bf16_t* W1pT_lo = (bf16_t*)w;  w += (size_t)P_HID * P_HID * 2;
    bf16_t* W2pT_hi = (bf16_t*)w;  w += (size_t)MAX_P * P_HID * 2;
    bf16_t* W2pT_lo = (bf16_t*)w;  w += (size_t)MAX_P * P_HID * 2;
    bf16_t* W1hT_hi = (bf16_t*)w;  w += (size_t)H_HID * H_HID * 2;
    bf16_t* W1hT_lo = (bf16_t*)w;  w += (size_t)H_HID * H_HID * 2;
    bf16_t* W2hT_hi = (bf16_t*)w;  w += (size_t)HE_PAD * H_HID * 2;
    bf16_t* W2hT_lo = (bf16_t*)w;  w += (size_t)HE_PAD * H_HID * 2;
    int*    ws_jj   = (int*)w;     w += E_MAX * 4;

    // split-K partials alias the pA planes (16 MB, dead after gemm_pack):
    // P: [128 tiles][4][32][128] f32 = 8 MB, H: +8 MB.
    float* part_base = (float*)pA_hi;

    // ---- 1: fused prep ----
    PrepArgs pa;
    pa.ph = particle_h; pa.hh = hyperedge_h;
    pa.W1p = W1_p; pa.W2p = W2_p; pa.W1h = W1_h; pa.W2h = W2_h;
    pa.pA_hi = pA_hi; pa.pA_lo = pA_lo; pa.hA_hi = hA_hi; pa.hA_lo = hA_lo;
    pa.W1pT_hi = W1pT_hi; pa.W1pT_lo = W1pT_lo;
    pa.W2pT_hi = W2pT_hi; pa.W2pT_lo = W2pT_lo;
    pa.W1hT_hi = W1hT_hi; pa.W1hT_lo = W1hT_lo;
    pa.W2hT_hi = W2hT_hi; pa.W2hT_lo = W2hT_lo;
    pa.out_ei = out_ei; pa.ws_jj = ws_jj;
    prep_all<<<7648, 256, 0, stream>>>(pa);

    // ---- 2: packed hidden GEMMs (R4-proven + XCD chunk swizzle) ----
    {
        GemmP P = {}, H = {};
        P.Ahi = pA_hi;  P.Alo = pA_lo;  P.BThi = W1pT_hi; P.BTlo = W1pT_lo;
        P.bias = b1_p;  P.Chi = hidp_hi; P.Clo = hidp_lo;
        P.N = P_HID; P.K = P_HID; P.nx = P_HID / 128;         // 8 -> 512 blocks
        H.Ahi = hA_hi;  H.Alo = hA_lo;  H.BThi = W1hT_hi; H.BTlo = W1hT_lo;
        H.bias = b1_h;  H.Chi = hidh_hi; H.Clo = hidh_lo;
        H.N = H_HID; H.K = H_HID; H.nx = H_HID / 128;         // 4 -> 256 blocks
        const int pB = (B_SZ / 64) * P.nx;                    // 512
        const int hB = (B_SZ / 64) * H.nx;                    // 256
        gemm_pack<64><<<pB + hB, 256, 0, stream>>>(P, H, pB);
    }

    // ---- 3a: split-K x4 logit GEMM partials (fence-free) ----
    {
        PartP P = {}, H = {};
        P.Ahi = hidp_hi; P.Alo = hidp_lo; P.BThi = W2pT_hi; P.BTlo = W2pT_lo;
        P.part = part_base; P.K = P_HID;
        H.Ahi = hidh_hi; H.Alo = hidh_lo; H.BThi = W2hT_hi; H.BTlo = W2hT_lo;
        H.part = part_base + (size_t)128 * 4 * 32 * 128; H.K = H_HID;
        const int pB = (B_SZ / 32) * 4;                       // 512
        const int hB = (B_SZ / 32) * 4;                       // 512
        gemm_logit_part<<<pB + hB, 256, 0, stream>>>(P, H, pB);
    }

    // ---- 3b: deterministic reduce + gumbel + fused edge_valid ----
    {
        RedEV P = {}, H = {};
        P.part = part_base; P.bias = b2_p; P.g = g_p;
        P.out_mask = out_pmask; P.out_n = out_np;
        P.jj = ws_jj; P.ev = out_ev; P.NV = MAX_P;
        H.part = part_base + (size_t)128 * 4 * 32 * 128; H.bias = b2_h; H.g = g_h;
        H.out_mask = out_hmask; H.out_n = out_nh;
        H.jj = nullptr; H.ev = nullptr; H.NV = MAX_HE;
        const int pB = B_SZ / 4;                              // 1024
        const int hB = B_SZ / 4;                              // 1024
        logit_reduce_ev<<<pB + hB, 256, 0, stream>>>(P, H, pB);
    }
}